// Round 1
// baseline (885.631 us; speedup 1.0000x reference)
//
#include <hip/hip_runtime.h>
#include <math.h>

// ---------------------------------------------------------------------------
// PinSageConv:
//   n   = relu(h_src @ q_w^T + q_b)            (100000 x 128)
//   m   = n[src_idx] * w[:,None]
//   agg = segment_sum(m, dst_idx, 50000)
//   ws  = clip(segment_sum(w, dst_idx), 1, inf)
//   z   = relu(concat(h_dst, agg/ws) @ w_w^T + w_b)
//   out = z / ||z||_row
// ---------------------------------------------------------------------------

#define TILE1_R 32
#define TILE2_R 16

// GEMM1: n = relu(h @ qw^T + qb). qw staged in LDS [col][k] with pad 132
// (16B-aligned rows, spreads banks). 32-row tile, 4 rows x 4 cols per thread.
__global__ __launch_bounds__(256) void k_gemm1(const float* __restrict__ h,
    const float* __restrict__ qw, const float* __restrict__ qb,
    float* __restrict__ nout, int nrows)
{
    __shared__ float ql[128][132];
    __shared__ float hl[TILE1_R][128];
    __shared__ float bias[128];

    for (int i = threadIdx.x; i < 128 * 128; i += 256)
        ql[i >> 7][i & 127] = qw[i];
    if (threadIdx.x < 128) bias[threadIdx.x] = qb[threadIdx.x];
    __syncthreads();

    const int c  = threadIdx.x & 31;   // col group: cols c, c+32, c+64, c+96
    const int g  = threadIdx.x >> 5;   // 0..7
    const int r0 = g * 4;              // 4 rows per thread

    for (int rb = blockIdx.x * TILE1_R; rb < nrows; rb += gridDim.x * TILE1_R) {
        // stage 32x128 h tile (float4 coalesced)
        for (int i = threadIdx.x * 4; i < TILE1_R * 128; i += 256 * 4) {
            int r = i >> 7, k = i & 127;
            int gr = rb + r;
            float4 v;
            if (gr < nrows) v = *(const float4*)&h[(size_t)gr * 128 + k];
            else            v = make_float4(0.f, 0.f, 0.f, 0.f);
            *(float4*)&hl[r][k] = v;
        }
        __syncthreads();

        float acc[4][4];
        #pragma unroll
        for (int j = 0; j < 4; ++j)
            #pragma unroll
            for (int i = 0; i < 4; ++i) acc[j][i] = 0.f;

        #pragma unroll 8
        for (int k = 0; k < 128; k += 4) {
            float4 hv[4], qv[4];
            #pragma unroll
            for (int j = 0; j < 4; ++j) hv[j] = *(const float4*)&hl[r0 + j][k];
            #pragma unroll
            for (int i = 0; i < 4; ++i) qv[i] = *(const float4*)&ql[c + 32 * i][k];
            #pragma unroll
            for (int j = 0; j < 4; ++j)
                #pragma unroll
                for (int i = 0; i < 4; ++i) {
                    acc[j][i] = fmaf(hv[j].x, qv[i].x, acc[j][i]);
                    acc[j][i] = fmaf(hv[j].y, qv[i].y, acc[j][i]);
                    acc[j][i] = fmaf(hv[j].z, qv[i].z, acc[j][i]);
                    acc[j][i] = fmaf(hv[j].w, qv[i].w, acc[j][i]);
                }
        }

        #pragma unroll
        for (int j = 0; j < 4; ++j) {
            int gr = rb + r0 + j;
            if (gr < nrows) {
                #pragma unroll
                for (int i = 0; i < 4; ++i) {
                    int col = c + 32 * i;
                    nout[(size_t)gr * 128 + col] = fmaxf(acc[j][i] + bias[col], 0.f);
                }
            }
        }
        __syncthreads();
    }
}

// Edge scatter: one wave per edge. Lane handles 2 of the 128 features.
__global__ __launch_bounds__(256) void k_edges(const float* __restrict__ nsrc,
    const float* __restrict__ w, const int* __restrict__ src,
    const int* __restrict__ dst, float* __restrict__ agg,
    float* __restrict__ wsum, int nedges)
{
    const int lane   = threadIdx.x & 63;
    const int wave   = (blockIdx.x * 256 + threadIdx.x) >> 6;
    const int nwaves = (gridDim.x * 256) >> 6;
    for (int e = wave; e < nedges; e += nwaves) {
        int   s  = src[e];
        int   d  = dst[e];
        float we = w[e];
        float2 v = *(const float2*)&nsrc[(size_t)s * 128 + lane * 2];
        float* ap = &agg[(size_t)d * 128 + lane * 2];
        atomicAdd(ap,     v.x * we);
        atomicAdd(ap + 1, v.y * we);
        if (lane == 0) atomicAdd(&wsum[d], we);
    }
}

// GEMM2 + row L2-norm. w_w (128x256) staged in LDS pad 260 (16B-aligned).
// 16-row tile; 2 rows x 4 cols per thread; norm via half-wave shfl reduce.
__global__ __launch_bounds__(256) void k_gemm2(const float* __restrict__ h,
    const float* __restrict__ agg, const float* __restrict__ wsum,
    const float* __restrict__ ww, const float* __restrict__ wb,
    float* __restrict__ out, int nrows)
{
    __shared__ float wl[128][260];
    __shared__ float zl[TILE2_R][256];
    __shared__ float bias[128];

    for (int i = threadIdx.x; i < 128 * 256; i += 256)
        wl[i >> 8][i & 255] = ww[i];
    if (threadIdx.x < 128) bias[threadIdx.x] = wb[threadIdx.x];
    __syncthreads();

    const int c  = threadIdx.x & 31;
    const int g  = threadIdx.x >> 5;   // 0..7
    const int r0 = g * 2;              // 2 rows per thread

    for (int rb = blockIdx.x * TILE2_R; rb < nrows; rb += gridDim.x * TILE2_R) {
        // stage z tile: cols 0..127 = h_dst, cols 128..255 = agg/ws
        for (int i = threadIdx.x; i < TILE2_R * 256; i += 256) {
            int r = i >> 8, k = i & 255;
            int gr = rb + r;
            float v = 0.f;
            if (gr < nrows) {
                if (k < 128) {
                    v = h[(size_t)gr * 128 + k];
                } else {
                    float s = fmaxf(wsum[gr], 1.f);
                    v = agg[(size_t)gr * 128 + (k - 128)] / s;
                }
            }
            zl[r][k] = v;
        }
        __syncthreads();

        float acc[2][4];
        #pragma unroll
        for (int i = 0; i < 4; ++i) { acc[0][i] = 0.f; acc[1][i] = 0.f; }

        #pragma unroll 8
        for (int k = 0; k < 256; k += 4) {
            float4 z0 = *(const float4*)&zl[r0][k];
            float4 z1 = *(const float4*)&zl[r0 + 1][k];
            #pragma unroll
            for (int i = 0; i < 4; ++i) {
                float4 wv = *(const float4*)&wl[c + 32 * i][k];
                acc[0][i] = fmaf(z0.x, wv.x, acc[0][i]);
                acc[0][i] = fmaf(z0.y, wv.y, acc[0][i]);
                acc[0][i] = fmaf(z0.z, wv.z, acc[0][i]);
                acc[0][i] = fmaf(z0.w, wv.w, acc[0][i]);
                acc[1][i] = fmaf(z1.x, wv.x, acc[1][i]);
                acc[1][i] = fmaf(z1.y, wv.y, acc[1][i]);
                acc[1][i] = fmaf(z1.z, wv.z, acc[1][i]);
                acc[1][i] = fmaf(z1.w, wv.w, acc[1][i]);
            }
        }

        // relu + bias, then row L2-norm across the 32 lanes sharing this row
        float v0[4], v1[4];
        float s0 = 0.f, s1 = 0.f;
        #pragma unroll
        for (int i = 0; i < 4; ++i) {
            int col = c + 32 * i;
            v0[i] = fmaxf(acc[0][i] + bias[col], 0.f);
            v1[i] = fmaxf(acc[1][i] + bias[col], 0.f);
            s0 = fmaf(v0[i], v0[i], s0);
            s1 = fmaf(v1[i], v1[i], s1);
        }
        #pragma unroll
        for (int m = 1; m < 32; m <<= 1) {
            s0 += __shfl_xor(s0, m);
            s1 += __shfl_xor(s1, m);
        }
        float n0 = sqrtf(s0); n0 = (n0 == 0.f) ? 1.f : n0;
        float n1 = sqrtf(s1); n1 = (n1 == 0.f) ? 1.f : n1;
        float i0 = 1.f / n0, i1 = 1.f / n1;

        int gr0 = rb + r0, gr1 = rb + r0 + 1;
        if (gr0 < nrows) {
            #pragma unroll
            for (int i = 0; i < 4; ++i)
                out[(size_t)gr0 * 128 + c + 32 * i] = v0[i] * i0;
        }
        if (gr1 < nrows) {
            #pragma unroll
            for (int i = 0; i < 4; ++i)
                out[(size_t)gr1 * 128 + c + 32 * i] = v1[i] * i1;
        }
        __syncthreads();
    }
}

extern "C" void kernel_launch(void* const* d_in, const int* in_sizes, int n_in,
                              void* d_out, int out_size, void* d_ws, size_t ws_size,
                              hipStream_t stream)
{
    const float* h   = (const float*)d_in[0];   // (N_SRC, 128)
    const float* wts = (const float*)d_in[1];   // (N_EDGES,)
    const int*   src = (const int*)d_in[2];
    const int*   dst = (const int*)d_in[3];
    // d_in[4] = num_dst scalar (device); derive from out_size instead
    const float* qw  = (const float*)d_in[5];   // (128,128)
    const float* qb  = (const float*)d_in[6];
    const float* www = (const float*)d_in[7];   // (128,256)
    const float* wb  = (const float*)d_in[8];
    float* out = (float*)d_out;

    const int n_src   = in_sizes[0] / 128;
    const int n_edges = in_sizes[1];
    const int n_dst   = out_size / 128;

    float* nbuf = (float*)d_ws;                     // n_src*128
    float* agg  = nbuf + (size_t)n_src * 128;       // n_dst*128
    float* wsum = agg + (size_t)n_dst * 128;        // n_dst

    // zero the accumulators (agg + wsum are contiguous)
    hipMemsetAsync(agg, 0, ((size_t)n_dst * 128 + n_dst) * sizeof(float), stream);

    dim3 blk(256);
    int g1 = (n_src + TILE1_R - 1) / TILE1_R;
    k_gemm1<<<g1, blk, 0, stream>>>(h, qw, qb, nbuf, n_src);

    k_edges<<<8192, blk, 0, stream>>>(nbuf, wts, src, dst, agg, wsum, n_edges);

    int g2 = (n_dst + TILE2_R - 1) / TILE2_R;
    k_gemm2<<<g2, blk, 0, stream>>>(h, agg, wsum, www, wb, out, n_dst);
}

// Round 2
// 428.640 us; speedup vs baseline: 2.0661x; 2.0661x over previous
//
#include <hip/hip_runtime.h>
#include <math.h>

// ---------------------------------------------------------------------------
// PinSageConv, round 2:
//   gemm1 : n = relu(h @ q_w^T + q_b)                  (100000 x 128)
//   sort  : counting-sort edges by dst (hist/scan/scatter)
//   gather: z2[d] = (sum_e n[src_e]*w_e) / max(sum w_e, 1)   -> d_out (in place)
//   gemm2 : out = rownorm(relu([h_dst | z2] @ w_w^T + w_b))  -> d_out (in place)
// ---------------------------------------------------------------------------

#define G1_TR 64
#define G2_TR 64

// ---------------- GEMM1: 512 thr, 64-row tile, 4x4/thread, q_w in LDS ------
__global__ __launch_bounds__(512) void k_gemm1(const float* __restrict__ h,
    const float* __restrict__ qw, const float* __restrict__ qb,
    float* __restrict__ nout, int nrows, int ntiles)
{
    __shared__ float ql[128 * 128];     // [col][k ^ swz]
    __shared__ float hl[G1_TR * 128];   // [r][k]
    __shared__ float bias[128];

    const int tid = threadIdx.x;

    // stage q_w swizzled (once per block)
    for (int f = tid; f < 128 * 32; f += 512) {        // float4 index
        int col = f >> 5;
        int k4  = (f & 31) << 2;
        float4 v = *(const float4*)&qw[col * 128 + k4];
        int swz = (col & 7) << 2;
        *(float4*)&ql[col * 128 + (k4 ^ swz)] = v;
    }
    if (tid < 128) bias[tid] = qb[tid];

    const int c   = tid & 31;
    const int r0  = (tid >> 5) << 2;    // 0..60
    const int swz = (c & 7) << 2;

    for (int t = blockIdx.x; t < ntiles; t += gridDim.x) {
        const int rb = t * G1_TR;
        __syncthreads();                 // protects hl overwrite (and ql, 1st iter)
        for (int f = tid; f < G1_TR * 32; f += 512) {
            int r  = f >> 5;
            int k4 = (f & 31) << 2;
            int gr = rb + r;
            float4 v = make_float4(0.f, 0.f, 0.f, 0.f);
            if (gr < nrows) v = *(const float4*)&h[(size_t)gr * 128 + k4];
            *(float4*)&hl[r * 128 + k4] = v;
        }
        __syncthreads();

        float acc[4][4] = {};
        #pragma unroll 8
        for (int k = 0; k < 128; k += 4) {
            float4 hv[4], qv[4];
            #pragma unroll
            for (int j = 0; j < 4; ++j)
                hv[j] = *(const float4*)&hl[(r0 + j) * 128 + k];
            #pragma unroll
            for (int i = 0; i < 4; ++i)
                qv[i] = *(const float4*)&ql[(c + 32 * i) * 128 + (k ^ swz)];
            #pragma unroll
            for (int j = 0; j < 4; ++j)
                #pragma unroll
                for (int i = 0; i < 4; ++i) {
                    acc[j][i] = fmaf(hv[j].x, qv[i].x, acc[j][i]);
                    acc[j][i] = fmaf(hv[j].y, qv[i].y, acc[j][i]);
                    acc[j][i] = fmaf(hv[j].z, qv[i].z, acc[j][i]);
                    acc[j][i] = fmaf(hv[j].w, qv[i].w, acc[j][i]);
                }
        }

        #pragma unroll
        for (int j = 0; j < 4; ++j) {
            int gr = rb + r0 + j;
            if (gr < nrows) {
                #pragma unroll
                for (int i = 0; i < 4; ++i) {
                    int col = c + 32 * i;
                    nout[(size_t)gr * 128 + col] = fmaxf(acc[j][i] + bias[col], 0.f);
                }
            }
        }
    }
}

// ---------------- edge counting sort ---------------------------------------
__global__ void k_hist(const int* __restrict__ dst, int* __restrict__ counts,
                       int nedges)
{
    for (int e = blockIdx.x * blockDim.x + threadIdx.x; e < nedges;
         e += gridDim.x * blockDim.x)
        atomicAdd(&counts[dst[e]], 1);
}

__global__ __launch_bounds__(1024) void k_scan(const int* __restrict__ counts,
    int* __restrict__ offs, int* __restrict__ cursor, int n, int total)
{
    __shared__ int wsum_[16];
    const int tid  = threadIdx.x;
    const int lane = tid & 63;
    const int wv   = tid >> 6;
    const int CH   = (n + 1023) >> 10;
    const int base = tid * CH;

    int s = 0;
    for (int i = 0; i < CH; ++i) {
        int idx = base + i;
        if (idx < n) s += counts[idx];
    }
    // inclusive wave scan
    int x = s;
    #pragma unroll
    for (int off = 1; off < 64; off <<= 1) {
        int y = __shfl_up(x, off);
        if (lane >= off) x += y;
    }
    if (lane == 63) wsum_[wv] = x;
    __syncthreads();
    if (tid == 0) {
        int r = 0;
        #pragma unroll
        for (int w = 0; w < 16; ++w) { int tt = wsum_[w]; wsum_[w] = r; r += tt; }
    }
    __syncthreads();
    int run = wsum_[wv] + x - s;   // exclusive prefix for this thread's chunk
    for (int i = 0; i < CH; ++i) {
        int idx = base + i;
        if (idx < n) {
            offs[idx]   = run;
            cursor[idx] = run;
            run += counts[idx];
        }
    }
    if (tid == 0) offs[n] = total;
}

__global__ void k_scatter(const int* __restrict__ src, const int* __restrict__ dst,
    const float* __restrict__ w, int* __restrict__ cursor,
    int* __restrict__ eSrc, float* __restrict__ eW, int nedges)
{
    for (int e = blockIdx.x * blockDim.x + threadIdx.x; e < nedges;
         e += gridDim.x * blockDim.x) {
        int d   = dst[e];
        int pos = atomicAdd(&cursor[d], 1);
        eSrc[pos] = src[e];
        eW[pos]   = w[e];
    }
}

// ---------------- gather: one wave per dst row -----------------------------
__global__ __launch_bounds__(256) void k_gather(const float* __restrict__ nsrc,
    const int* __restrict__ offs, const int* __restrict__ eSrc,
    const float* __restrict__ eW, float* __restrict__ z2out, int ndst)
{
    const int wave = (blockIdx.x * 256 + threadIdx.x) >> 6;
    const int lane = threadIdx.x & 63;
    if (wave >= ndst) return;
    const int j0 = offs[wave], j1 = offs[wave + 1];
    float a0 = 0.f, a1 = 0.f, ws = 0.f;
    for (int j = j0; j < j1; ++j) {
        int   s  = eSrc[j];
        float we = eW[j];
        float2 v = *(const float2*)&nsrc[(size_t)s * 128 + lane * 2];
        a0 = fmaf(v.x, we, a0);
        a1 = fmaf(v.y, we, a1);
        ws += we;
    }
    float dnm = fmaxf(ws, 1.f);
    float2 o; o.x = a0 / dnm; o.y = a1 / dnm;
    *(float2*)&z2out[(size_t)wave * 128 + lane * 2] = o;
}

// ---------------- GEMM2 + row L2-norm, in-place on d_out -------------------
// z = [ h_dst (K 0..127) | z2 (K 128..255) ], out = rownorm(relu(z @ ww^T + wb))
__global__ __launch_bounds__(512) void k_gemm2(const float* __restrict__ h,
    const float* __restrict__ ww, const float* __restrict__ wb,
    float* __restrict__ zio, int nrows, int ntiles)
{
    __shared__ float wl[128 * 256];     // [col][k ^ swz]
    __shared__ float zl[G2_TR * 64];    // [r][k within quarter]
    __shared__ float bias[128];

    const int tid = threadIdx.x;

    for (int f = tid; f < 128 * 64; f += 512) {        // float4 index
        int col = f >> 6;
        int k4  = (f & 63) << 2;
        float4 v = *(const float4*)&ww[col * 256 + k4];
        int swz = (col & 7) << 2;
        *(float4*)&wl[col * 256 + (k4 ^ swz)] = v;
    }
    if (tid < 128) bias[tid] = wb[tid];

    const int c   = tid & 31;
    const int r0  = (tid >> 5) << 2;
    const int swz = (c & 7) << 2;

    for (int t = blockIdx.x; t < ntiles; t += gridDim.x) {
        const int rb = t * G2_TR;
        float acc[4][4] = {};

        #pragma unroll
        for (int kq = 0; kq < 4; ++kq) {
            __syncthreads();            // protect zl overwrite (and wl, 1st iter)
            const float* srcb = (kq < 2) ? h : zio;
            const int koff = (kq & 1) * 64;
            for (int f = tid; f < G2_TR * 16; f += 512) {
                int r  = f >> 4;
                int k4 = (f & 15) << 2;
                int gr = rb + r;
                float4 v = make_float4(0.f, 0.f, 0.f, 0.f);
                if (gr < nrows) v = *(const float4*)&srcb[(size_t)gr * 128 + koff + k4];
                *(float4*)&zl[r * 64 + k4] = v;
            }
            __syncthreads();

            const int kb = kq * 64;
            #pragma unroll 4
            for (int k = 0; k < 64; k += 4) {
                float4 zv[4], wv[4];
                #pragma unroll
                for (int j = 0; j < 4; ++j)
                    zv[j] = *(const float4*)&zl[(r0 + j) * 64 + k];
                #pragma unroll
                for (int i = 0; i < 4; ++i)
                    wv[i] = *(const float4*)&wl[(c + 32 * i) * 256 + ((kb + k) ^ swz)];
                #pragma unroll
                for (int j = 0; j < 4; ++j)
                    #pragma unroll
                    for (int i = 0; i < 4; ++i) {
                        acc[j][i] = fmaf(zv[j].x, wv[i].x, acc[j][i]);
                        acc[j][i] = fmaf(zv[j].y, wv[i].y, acc[j][i]);
                        acc[j][i] = fmaf(zv[j].z, wv[i].z, acc[j][i]);
                        acc[j][i] = fmaf(zv[j].w, wv[i].w, acc[j][i]);
                    }
            }
        }

        // bias + relu, then row L2-norm across the 32 lanes of this group
        float v[4][4];
        float ss[4] = {0.f, 0.f, 0.f, 0.f};
        #pragma unroll
        for (int j = 0; j < 4; ++j)
            #pragma unroll
            for (int i = 0; i < 4; ++i) {
                int col = c + 32 * i;
                v[j][i] = fmaxf(acc[j][i] + bias[col], 0.f);
                ss[j] = fmaf(v[j][i], v[j][i], ss[j]);
            }
        #pragma unroll
        for (int m = 1; m < 32; m <<= 1) {
            #pragma unroll
            for (int j = 0; j < 4; ++j) ss[j] += __shfl_xor(ss[j], m);
        }
        #pragma unroll
        for (int j = 0; j < 4; ++j) {
            float nr = sqrtf(ss[j]);
            nr = (nr == 0.f) ? 1.f : nr;
            float inv = 1.f / nr;
            int gr = rb + r0 + j;
            if (gr < nrows) {
                #pragma unroll
                for (int i = 0; i < 4; ++i)
                    zio[(size_t)gr * 128 + c + 32 * i] = v[j][i] * inv;
            }
        }
    }
}

// ---------------------------------------------------------------------------
extern "C" void kernel_launch(void* const* d_in, const int* in_sizes, int n_in,
                              void* d_out, int out_size, void* d_ws, size_t ws_size,
                              hipStream_t stream)
{
    const float* h   = (const float*)d_in[0];   // (N_SRC, 128)
    const float* wts = (const float*)d_in[1];   // (N_EDGES,)
    const int*   src = (const int*)d_in[2];
    const int*   dst = (const int*)d_in[3];
    const float* qw  = (const float*)d_in[5];   // (128,128)
    const float* qb  = (const float*)d_in[6];
    const float* www = (const float*)d_in[7];   // (128,256)
    const float* wb  = (const float*)d_in[8];
    float* out = (float*)d_out;

    const int n_src   = in_sizes[0] / 128;
    const int n_edges = in_sizes[1];
    const int n_dst   = out_size / 128;

    // workspace layout
    float* nbuf   = (float*)d_ws;                        // n_src*128 f32
    int*   eSrc   = (int*)(nbuf + (size_t)n_src * 128);  // n_edges int
    float* eW     = (float*)(eSrc + n_edges);            // n_edges f32
    int*   counts = (int*)(eW + n_edges);                // n_dst
    int*   offs   = counts + n_dst;                      // n_dst + 1
    int*   cursor = offs + n_dst + 1;                    // n_dst

    hipMemsetAsync(counts, 0, (size_t)n_dst * sizeof(int), stream);

    const int t1 = (n_src + G1_TR - 1) / G1_TR;
    k_gemm1<<<256, 512, 0, stream>>>(h, qw, qb, nbuf, n_src, t1);

    k_hist<<<1024, 256, 0, stream>>>(dst, counts, n_edges);
    k_scan<<<1, 1024, 0, stream>>>(counts, offs, cursor, n_dst, n_edges);
    k_scatter<<<1024, 256, 0, stream>>>(src, dst, wts, cursor, eSrc, eW, n_edges);

    const int gblocks = (n_dst + 3) / 4;                 // 4 waves (dst rows) / block
    k_gather<<<gblocks, 256, 0, stream>>>(nbuf, offs, eSrc, eW, out, n_dst);

    const int t2 = (n_dst + G2_TR - 1) / G2_TR;
    k_gemm2<<<256, 512, 0, stream>>>(h, www, wb, out, n_dst, t2);
}

// Round 3
// 316.153 us; speedup vs baseline: 2.8013x; 1.3558x over previous
//
#include <hip/hip_runtime.h>
#include <math.h>

// ---------------------------------------------------------------------------
// PinSageConv, round 3:
//   gemm1 : n = relu(h @ q_w^T + q_b)                  (100000 x 128)
//   sort  : counting-sort edges by dst (hist / 3-kernel hierarchical scan /
//           scatter)   [round-2's single-block scan was 127 us -- latency-
//           serialized on one CU; now 49 blocks, coalesced]
//   gather: z2[d] = (sum_e n[src_e]*w_e) / max(sum w_e, 1)   -> d_out
//   gemm2 : out = rownorm(relu([h_dst | z2] @ w_w^T + w_b))  -> d_out in place
//   GEMMs use T14 async-stage: next tile global->regs issued under compute.
// ---------------------------------------------------------------------------

#define G1_TR 64
#define G2_TR 64

// ---------------- GEMM1: 512 thr, 64-row tile, 4x4/thread, q_w in LDS ------
__global__ __launch_bounds__(512) void k_gemm1(const float* __restrict__ h,
    const float* __restrict__ qw, const float* __restrict__ qb,
    float* __restrict__ nout, int nrows, int ntiles)
{
    __shared__ float ql[128 * 128];     // [col][k ^ swz]
    __shared__ float hl[G1_TR * 128];   // [r][k]
    __shared__ float bias[128];

    const int tid = threadIdx.x;

    // stage q_w swizzled (once per block)
    for (int f = tid; f < 128 * 32; f += 512) {        // float4 index
        int col = f >> 5;
        int k4  = (f & 31) << 2;
        float4 v = *(const float4*)&qw[col * 128 + k4];
        int swz = (col & 7) << 2;
        *(float4*)&ql[col * 128 + (k4 ^ swz)] = v;
    }
    if (tid < 128) bias[tid] = qb[tid];

    const int c   = tid & 31;
    const int r0  = (tid >> 5) << 2;    // 0..60
    const int swz = (c & 7) << 2;

    // prologue: prefetch first tile into regs (4 float4 / thread)
    float4 pre[4];
    {
        int t0 = blockIdx.x;
        if (t0 < ntiles) {
            #pragma unroll
            for (int i = 0; i < 4; ++i) {
                int f  = tid + i * 512;
                int r  = f >> 5;
                int k4 = (f & 31) << 2;
                int gr = t0 * G1_TR + r;
                pre[i] = (gr < nrows) ? *(const float4*)&h[(size_t)gr * 128 + k4]
                                      : make_float4(0.f, 0.f, 0.f, 0.f);
            }
        }
    }

    for (int t = blockIdx.x; t < ntiles; t += gridDim.x) {
        __syncthreads();                 // prev compute done reading hl; ql ready (1st)
        #pragma unroll
        for (int i = 0; i < 4; ++i) {
            int f  = tid + i * 512;
            int r  = f >> 5;
            int k4 = (f & 31) << 2;
            *(float4*)&hl[r * 128 + k4] = pre[i];
        }
        __syncthreads();

        // issue next-tile loads; latency hides under the FMA loop below
        int nx = t + gridDim.x;
        if (nx < ntiles) {
            #pragma unroll
            for (int i = 0; i < 4; ++i) {
                int f  = tid + i * 512;
                int r  = f >> 5;
                int k4 = (f & 31) << 2;
                int gr = nx * G1_TR + r;
                pre[i] = (gr < nrows) ? *(const float4*)&h[(size_t)gr * 128 + k4]
                                      : make_float4(0.f, 0.f, 0.f, 0.f);
            }
        }

        float acc[4][4] = {};
        #pragma unroll 8
        for (int k = 0; k < 128; k += 4) {
            float4 hv[4], qv[4];
            #pragma unroll
            for (int j = 0; j < 4; ++j)
                hv[j] = *(const float4*)&hl[(r0 + j) * 128 + k];
            #pragma unroll
            for (int i = 0; i < 4; ++i)
                qv[i] = *(const float4*)&ql[(c + 32 * i) * 128 + (k ^ swz)];
            #pragma unroll
            for (int j = 0; j < 4; ++j)
                #pragma unroll
                for (int i = 0; i < 4; ++i) {
                    acc[j][i] = fmaf(hv[j].x, qv[i].x, acc[j][i]);
                    acc[j][i] = fmaf(hv[j].y, qv[i].y, acc[j][i]);
                    acc[j][i] = fmaf(hv[j].z, qv[i].z, acc[j][i]);
                    acc[j][i] = fmaf(hv[j].w, qv[i].w, acc[j][i]);
                }
        }

        const int rb = t * G1_TR;
        #pragma unroll
        for (int j = 0; j < 4; ++j) {
            int gr = rb + r0 + j;
            if (gr < nrows) {
                #pragma unroll
                for (int i = 0; i < 4; ++i) {
                    int col = c + 32 * i;
                    nout[(size_t)gr * 128 + col] = fmaxf(acc[j][i] + bias[col], 0.f);
                }
            }
        }
    }
}

// ---------------- edge counting sort ---------------------------------------
__global__ void k_hist(const int* __restrict__ dst, int* __restrict__ counts,
                       int nedges)
{
    for (int e = blockIdx.x * blockDim.x + threadIdx.x; e < nedges;
         e += gridDim.x * blockDim.x)
        atomicAdd(&counts[dst[e]], 1);
}

// block-level exclusive scan: one element per thread, coalesced
__global__ __launch_bounds__(1024) void k_scan_blk(const int* __restrict__ counts,
    int* __restrict__ offs, int* __restrict__ partials, int n)
{
    __shared__ int wtot[16];
    const int tid  = threadIdx.x;
    const int lane = tid & 63;
    const int wv   = tid >> 6;
    const int idx  = blockIdx.x * 1024 + tid;

    int v = (idx < n) ? counts[idx] : 0;
    int x = v;
    #pragma unroll
    for (int off = 1; off < 64; off <<= 1) {
        int y = __shfl_up(x, off);
        if (lane >= off) x += y;
    }
    if (lane == 63) wtot[wv] = x;
    __syncthreads();
    if (tid == 0) {
        int r = 0;
        #pragma unroll
        for (int w = 0; w < 16; ++w) { int t = wtot[w]; wtot[w] = r; r += t; }
    }
    __syncthreads();
    if (idx < n) offs[idx] = wtot[wv] + x - v;           // exclusive-in-block
    if (tid == 1023) partials[blockIdx.x] = wtot[15] + x; // block total
}

// scan the (<=64) block totals with one wave
__global__ void k_scan_part(int* __restrict__ partials, int nb)
{
    const int lane = threadIdx.x;          // blockDim = 64, nb <= 64
    int v = (lane < nb) ? partials[lane] : 0;
    int x = v;
    #pragma unroll
    for (int off = 1; off < 64; off <<= 1) {
        int y = __shfl_up(x, off);
        if (lane >= off) x += y;
    }
    if (lane < nb) partials[lane] = x - v; // exclusive
}

__global__ __launch_bounds__(1024) void k_scan_add(int* __restrict__ offs,
    int* __restrict__ cursor, const int* __restrict__ partials, int n, int total)
{
    const int idx = blockIdx.x * 1024 + threadIdx.x;
    if (idx < n) {
        int o = offs[idx] + partials[blockIdx.x];
        offs[idx]   = o;
        cursor[idx] = o;
    }
    if (idx == 0) offs[n] = total;
}

__global__ void k_scatter(const int* __restrict__ src, const int* __restrict__ dst,
    const float* __restrict__ w, int* __restrict__ cursor,
    int* __restrict__ eSrc, float* __restrict__ eW, int nedges)
{
    for (int e = blockIdx.x * blockDim.x + threadIdx.x; e < nedges;
         e += gridDim.x * blockDim.x) {
        int d   = dst[e];
        int pos = atomicAdd(&cursor[d], 1);
        eSrc[pos] = src[e];
        eW[pos]   = w[e];
    }
}

// ---------------- gather: one wave per dst row -----------------------------
__global__ __launch_bounds__(256) void k_gather(const float* __restrict__ nsrc,
    const int* __restrict__ offs, const int* __restrict__ eSrc,
    const float* __restrict__ eW, float* __restrict__ z2out, int ndst)
{
    const int wave = (blockIdx.x * 256 + threadIdx.x) >> 6;
    const int lane = threadIdx.x & 63;
    if (wave >= ndst) return;
    const int j0 = offs[wave], j1 = offs[wave + 1];
    float a0 = 0.f, a1 = 0.f, ws = 0.f;
    for (int j = j0; j < j1; ++j) {
        int   s  = eSrc[j];
        float we = eW[j];
        float2 v = *(const float2*)&nsrc[(size_t)s * 128 + lane * 2];
        a0 = fmaf(v.x, we, a0);
        a1 = fmaf(v.y, we, a1);
        ws += we;
    }
    float dnm = fmaxf(ws, 1.f);
    float2 o; o.x = a0 / dnm; o.y = a1 / dnm;
    *(float2*)&z2out[(size_t)wave * 128 + lane * 2] = o;
}

// ---------------- GEMM2 + row L2-norm, in-place on d_out -------------------
// z = [ h_dst (K 0..127) | z2 (K 128..255) ], out = rownorm(relu(z @ ww^T + wb))
__global__ __launch_bounds__(512) void k_gemm2(const float* __restrict__ h,
    const float* __restrict__ ww, const float* __restrict__ wb,
    float* __restrict__ zio, int nrows, int ntiles)
{
    __shared__ float wl[128 * 256];     // [col][k ^ swz]
    __shared__ float zl[G2_TR * 64];    // [r][k within quarter]
    __shared__ float bias[128];

    const int tid = threadIdx.x;

    for (int f = tid; f < 128 * 64; f += 512) {        // float4 index
        int col = f >> 6;
        int k4  = (f & 63) << 2;
        float4 v = *(const float4*)&ww[col * 256 + k4];
        int swz = (col & 7) << 2;
        *(float4*)&wl[col * 256 + (k4 ^ swz)] = v;
    }
    if (tid < 128) bias[tid] = wb[tid];

    const int c   = tid & 31;
    const int r0  = (tid >> 5) << 2;
    const int swz = (c & 7) << 2;

    // prologue: prefetch (tile blockIdx.x, quarter 0) -> regs (2 float4)
    float4 pre[2];
    {
        int t0 = blockIdx.x;
        if (t0 < ntiles) {
            #pragma unroll
            for (int i = 0; i < 2; ++i) {
                int f  = tid + i * 512;
                int r  = f >> 4;
                int k4 = (f & 15) << 2;
                int gr = t0 * G2_TR + r;
                pre[i] = (gr < nrows) ? *(const float4*)&h[(size_t)gr * 128 + k4]
                                      : make_float4(0.f, 0.f, 0.f, 0.f);
            }
        }
    }

    for (int t = blockIdx.x; t < ntiles; t += gridDim.x) {
        float acc[4][4] = {};

        #pragma unroll
        for (int kq = 0; kq < 4; ++kq) {
            __syncthreads();            // prev quarter's reads of zl done; wl ready (1st)
            #pragma unroll
            for (int i = 0; i < 2; ++i) {
                int f  = tid + i * 512;
                int r  = f >> 4;
                int k4 = (f & 15) << 2;
                *(float4*)&zl[r * 64 + k4] = pre[i];
            }
            __syncthreads();

            // prefetch next (tile, quarter) in sequence
            int nt = t, nq = kq + 1;
            if (nq == 4) { nq = 0; nt = t + gridDim.x; }
            if (nt < ntiles) {
                const float* srcb = (nq < 2) ? h : zio;
                const int koff = (nq & 1) * 64;
                #pragma unroll
                for (int i = 0; i < 2; ++i) {
                    int f  = tid + i * 512;
                    int r  = f >> 4;
                    int k4 = (f & 15) << 2;
                    int gr = nt * G2_TR + r;
                    pre[i] = (gr < nrows)
                        ? *(const float4*)&srcb[(size_t)gr * 128 + koff + k4]
                        : make_float4(0.f, 0.f, 0.f, 0.f);
                }
            }

            const int kb = kq * 64;
            #pragma unroll 4
            for (int k = 0; k < 64; k += 4) {
                float4 zv[4], wv[4];
                #pragma unroll
                for (int j = 0; j < 4; ++j)
                    zv[j] = *(const float4*)&zl[(r0 + j) * 64 + k];
                #pragma unroll
                for (int i = 0; i < 4; ++i)
                    wv[i] = *(const float4*)&wl[(c + 32 * i) * 256 + ((kb + k) ^ swz)];
                #pragma unroll
                for (int j = 0; j < 4; ++j)
                    #pragma unroll
                    for (int i = 0; i < 4; ++i) {
                        acc[j][i] = fmaf(zv[j].x, wv[i].x, acc[j][i]);
                        acc[j][i] = fmaf(zv[j].y, wv[i].y, acc[j][i]);
                        acc[j][i] = fmaf(zv[j].z, wv[i].z, acc[j][i]);
                        acc[j][i] = fmaf(zv[j].w, wv[i].w, acc[j][i]);
                    }
            }
        }

        // bias + relu, then row L2-norm across the 32 lanes of this group
        float v[4][4];
        float ss[4] = {0.f, 0.f, 0.f, 0.f};
        #pragma unroll
        for (int j = 0; j < 4; ++j)
            #pragma unroll
            for (int i = 0; i < 4; ++i) {
                int col = c + 32 * i;
                v[j][i] = fmaxf(acc[j][i] + bias[col], 0.f);
                ss[j] = fmaf(v[j][i], v[j][i], ss[j]);
            }
        #pragma unroll
        for (int m = 1; m < 32; m <<= 1) {
            #pragma unroll
            for (int j = 0; j < 4; ++j) ss[j] += __shfl_xor(ss[j], m);
        }
        const int rb = t * G2_TR;
        #pragma unroll
        for (int j = 0; j < 4; ++j) {
            float nr = sqrtf(ss[j]);
            nr = (nr == 0.f) ? 1.f : nr;
            float inv = 1.f / nr;
            int gr = rb + r0 + j;
            if (gr < nrows) {
                #pragma unroll
                for (int i = 0; i < 4; ++i)
                    zio[(size_t)gr * 128 + c + 32 * i] = v[j][i] * inv;
            }
        }
    }
}

// ---------------------------------------------------------------------------
extern "C" void kernel_launch(void* const* d_in, const int* in_sizes, int n_in,
                              void* d_out, int out_size, void* d_ws, size_t ws_size,
                              hipStream_t stream)
{
    const float* h   = (const float*)d_in[0];   // (N_SRC, 128)
    const float* wts = (const float*)d_in[1];   // (N_EDGES,)
    const int*   src = (const int*)d_in[2];
    const int*   dst = (const int*)d_in[3];
    const float* qw  = (const float*)d_in[5];   // (128,128)
    const float* qb  = (const float*)d_in[6];
    const float* www = (const float*)d_in[7];   // (128,256)
    const float* wb  = (const float*)d_in[8];
    float* out = (float*)d_out;

    const int n_src   = in_sizes[0] / 128;
    const int n_edges = in_sizes[1];
    const int n_dst   = out_size / 128;

    // workspace layout
    float* nbuf   = (float*)d_ws;                        // n_src*128 f32
    int*   eSrc   = (int*)(nbuf + (size_t)n_src * 128);  // n_edges int
    float* eW     = (float*)(eSrc + n_edges);            // n_edges f32
    int*   counts = (int*)(eW + n_edges);                // n_dst
    int*   offs   = counts + n_dst;                      // n_dst + 1
    int*   cursor = offs + n_dst + 1;                    // n_dst
    int*   parts  = cursor + n_dst;                      // <=64

    hipMemsetAsync(counts, 0, (size_t)n_dst * sizeof(int), stream);

    const int t1 = (n_src + G1_TR - 1) / G1_TR;
    k_gemm1<<<256, 512, 0, stream>>>(h, qw, qb, nbuf, n_src, t1);

    k_hist<<<1024, 256, 0, stream>>>(dst, counts, n_edges);

    const int nb = (n_dst + 1023) / 1024;                // 49 for n_dst=50000
    k_scan_blk<<<nb, 1024, 0, stream>>>(counts, offs, parts, n_dst);
    k_scan_part<<<1, 64, 0, stream>>>(parts, nb);
    k_scan_add<<<nb, 1024, 0, stream>>>(offs, cursor, parts, n_dst, n_edges);

    k_scatter<<<1024, 256, 0, stream>>>(src, dst, wts, cursor, eSrc, eW, n_edges);

    const int gblocks = (n_dst + 3) / 4;                 // 4 waves (dst rows) / block
    k_gather<<<gblocks, 256, 0, stream>>>(nbuf, offs, eSrc, eW, out, n_dst);

    const int t2 = (n_dst + G2_TR - 1) / G2_TR;
    k_gemm2<<<256, 512, 0, stream>>>(h, www, wb, out, n_dst, t2);
}

// Round 4
// 226.007 us; speedup vs baseline: 3.9186x; 1.3989x over previous
//
#include <hip/hip_runtime.h>
#include <math.h>

// ---------------------------------------------------------------------------
// PinSageConv, round 4: bf16 MFMA GEMMs, bf16 n/z2 buffers.
//   cvtW  : qw, ww f32 -> bf16 (L2-hot B operands, read direct from global)
//   gemm1 : n = relu(h @ q_w^T + q_b)        bf16 MFMA, out bf16
//   sort  : hist / hierarchical scan / scatter (unchanged, passed R3)
//   gather: z2[d] = (sum n[src]*w)/max(sum w,1)  bf16 in/out, f32 accum
//   gemm2 : out = rownorm(relu([h_dst|z2] @ w_w^T + w_b))  bf16 MFMA, f32 out
// MFMA 16x16x32_bf16 layouts (m89-verified):
//   A/B frag: lane holds [row|col = lane&15][k = (lane>>4)*8 + j], j=0..7
//   D frag  : col = lane&15, row = (lane>>4)*4 + reg
// ---------------------------------------------------------------------------

typedef __attribute__((ext_vector_type(8))) short  short8;
typedef __attribute__((ext_vector_type(8))) __bf16 bf16x8;
typedef __attribute__((ext_vector_type(4))) float  f32x4;

#define MFMA16(a, b, c) __builtin_amdgcn_mfma_f32_16x16x32_bf16( \
    __builtin_bit_cast(bf16x8, (a)), __builtin_bit_cast(bf16x8, (b)), (c), 0, 0, 0)

__device__ __forceinline__ ushort f2bf(float x) {            // RNE f32->bf16
    unsigned u = __float_as_uint(x);
    return (ushort)((u + 0x7fffu + ((u >> 16) & 1u)) >> 16);
}
__device__ __forceinline__ float bfhi(unsigned p) { return __uint_as_float(p & 0xffff0000u); }
__device__ __forceinline__ float bflo(unsigned p) { return __uint_as_float(p << 16); }

// ---------------- weight conversion (qw 16384, ww 32768 f32) ---------------
__global__ __launch_bounds__(256) void k_cvtW(const float* __restrict__ qw,
    const float* __restrict__ ww, ushort* __restrict__ qwb, ushort* __restrict__ wwb)
{
    int i = (blockIdx.x * 256 + threadIdx.x) * 4;
    if (i < 16384) {
        float4 v = *(const float4*)&qw[i];
        ushort4 r; r.x = f2bf(v.x); r.y = f2bf(v.y); r.z = f2bf(v.z); r.w = f2bf(v.w);
        *(ushort4*)&qwb[i] = r;
    } else {
        int j = i - 16384;
        if (j < 32768) {
            float4 v = *(const float4*)&ww[j];
            ushort4 r; r.x = f2bf(v.x); r.y = f2bf(v.y); r.z = f2bf(v.z); r.w = f2bf(v.w);
            *(ushort4*)&wwb[j] = r;
        }
    }
}

// ---------------- GEMM1: 64-row tile, 256 thr (4 waves), MFMA --------------
// A = h rows (f32 -> bf16 LDS, 16 slots/row, slot ^= row&7), B = qwb global.
__global__ __launch_bounds__(256) void k_gemm1(const float* __restrict__ h,
    const ushort* __restrict__ qwb, const float* __restrict__ qb,
    ushort* __restrict__ nout, int nrows)
{
    __shared__ __align__(16) ushort aL[64 * 128];
    const int tid = threadIdx.x;
    const int rb  = blockIdx.x * 64;

    {   // stage A: rows rg*16+(tid>>4), k covered by slot sl=tid&15 (8 f32 each)
        const int rr = tid >> 4, sl = tid & 15;
        #pragma unroll
        for (int rg = 0; rg < 4; ++rg) {
            int row = rg * 16 + rr, gr = rb + row;
            float4 v0 = make_float4(0.f,0.f,0.f,0.f), v1 = v0;
            if (gr < nrows) {
                v0 = *(const float4*)&h[(size_t)gr * 128 + sl * 8];
                v1 = *(const float4*)&h[(size_t)gr * 128 + sl * 8 + 4];
            }
            ushort t[8] = { f2bf(v0.x), f2bf(v0.y), f2bf(v0.z), f2bf(v0.w),
                            f2bf(v1.x), f2bf(v1.y), f2bf(v1.z), f2bf(v1.w) };
            int slot = sl ^ (row & 7);
            *(short8*)&aL[row * 128 + slot * 8] = *(short8*)t;
        }
    }
    __syncthreads();

    const int w = tid >> 6, l = tid & 63;
    const int lr = l & 15, lk = l >> 4;

    float bs[8];
    #pragma unroll
    for (int nt = 0; nt < 8; ++nt) bs[nt] = qb[nt * 16 + lr];

    short8 a[4];
    #pragma unroll
    for (int ks = 0; ks < 4; ++ks) {
        int row  = 16 * w + lr;
        int slot = (ks * 4 + lk) ^ (row & 7);
        a[ks] = *(const short8*)&aL[row * 128 + slot * 8];
    }

    f32x4 acc[8];
    #pragma unroll
    for (int nt = 0; nt < 8; ++nt) acc[nt] = (f32x4){0.f, 0.f, 0.f, 0.f};

    #pragma unroll
    for (int nt = 0; nt < 8; ++nt)
        #pragma unroll
        for (int ks = 0; ks < 4; ++ks) {
            short8 b = *(const short8*)&qwb[(size_t)(nt * 16 + lr) * 128 + ks * 32 + lk * 8];
            acc[nt] = MFMA16(a[ks], b, acc[nt]);
        }

    #pragma unroll
    for (int v = 0; v < 4; ++v) {
        int gr = rb + 16 * w + lk * 4 + v;
        if (gr < nrows) {
            #pragma unroll
            for (int nt = 0; nt < 8; ++nt) {
                float x = fmaxf(acc[nt][v] + bs[nt], 0.f);
                nout[(size_t)gr * 128 + nt * 16 + lr] = f2bf(x);
            }
        }
    }
}

// ---------------- edge counting sort (unchanged from R3) -------------------
__global__ void k_hist(const int* __restrict__ dst, int* __restrict__ counts, int nedges)
{
    for (int e = blockIdx.x * blockDim.x + threadIdx.x; e < nedges;
         e += gridDim.x * blockDim.x)
        atomicAdd(&counts[dst[e]], 1);
}

__global__ __launch_bounds__(1024) void k_scan_blk(const int* __restrict__ counts,
    int* __restrict__ offs, int* __restrict__ partials, int n)
{
    __shared__ int wtot[16];
    const int tid = threadIdx.x, lane = tid & 63, wv = tid >> 6;
    const int idx = blockIdx.x * 1024 + tid;
    int v = (idx < n) ? counts[idx] : 0;
    int x = v;
    #pragma unroll
    for (int off = 1; off < 64; off <<= 1) {
        int y = __shfl_up(x, off);
        if (lane >= off) x += y;
    }
    if (lane == 63) wtot[wv] = x;
    __syncthreads();
    if (tid == 0) {
        int r = 0;
        #pragma unroll
        for (int q = 0; q < 16; ++q) { int t = wtot[q]; wtot[q] = r; r += t; }
    }
    __syncthreads();
    if (idx < n) offs[idx] = wtot[wv] + x - v;
    if (tid == 1023) partials[blockIdx.x] = wtot[15] + x;
}

__global__ void k_scan_part(int* __restrict__ partials, int nb)
{
    const int lane = threadIdx.x;
    int v = (lane < nb) ? partials[lane] : 0;
    int x = v;
    #pragma unroll
    for (int off = 1; off < 64; off <<= 1) {
        int y = __shfl_up(x, off);
        if (lane >= off) x += y;
    }
    if (lane < nb) partials[lane] = x - v;
}

__global__ __launch_bounds__(1024) void k_scan_add(int* __restrict__ offs,
    int* __restrict__ cursor, const int* __restrict__ partials, int n, int total)
{
    const int idx = blockIdx.x * 1024 + threadIdx.x;
    if (idx < n) {
        int o = offs[idx] + partials[blockIdx.x];
        offs[idx] = o;
        cursor[idx] = o;
    }
    if (idx == 0) offs[n] = total;
}

__global__ void k_scatter(const int* __restrict__ src, const int* __restrict__ dst,
    const float* __restrict__ w, int* __restrict__ cursor,
    int* __restrict__ eSrc, float* __restrict__ eW, int nedges)
{
    for (int e = blockIdx.x * blockDim.x + threadIdx.x; e < nedges;
         e += gridDim.x * blockDim.x) {
        int d = dst[e];
        int pos = atomicAdd(&cursor[d], 1);
        eSrc[pos] = src[e];
        eW[pos]   = w[e];
    }
}

// ---------------- gather: one wave per dst row, bf16 in/out ----------------
__global__ __launch_bounds__(256) void k_gather(const ushort* __restrict__ nsrc,
    const int* __restrict__ offs, const int* __restrict__ eSrc,
    const float* __restrict__ eW, ushort* __restrict__ z2, int ndst)
{
    const int wave = (blockIdx.x * 256 + threadIdx.x) >> 6;
    const int lane = threadIdx.x & 63;
    if (wave >= ndst) return;
    const int j0 = offs[wave], j1 = offs[wave + 1];
    float a0 = 0.f, a1 = 0.f, ws = 0.f;
    for (int j = j0; j < j1; ++j) {
        int s = eSrc[j];
        float we = eW[j];
        unsigned p = *(const unsigned*)&nsrc[(size_t)s * 128 + lane * 2];
        a0 = fmaf(bflo(p), we, a0);
        a1 = fmaf(bfhi(p), we, a1);
        ws += we;
    }
    float dnm = fmaxf(ws, 1.f);
    unsigned o = (unsigned)f2bf(a0 / dnm) | ((unsigned)f2bf(a1 / dnm) << 16);
    *(unsigned*)&z2[(size_t)wave * 128 + lane * 2] = o;
}

// ---------------- GEMM2 + row L2-norm: 64-row tile, K=256, MFMA ------------
// A rows = [h_dst f32 (k 0..127) | z2 bf16 (k 128..255)] -> bf16 LDS,
// 32 slots/row, slot ^= row&7. B = wwb global. Out f32 with rownorm.
__global__ __launch_bounds__(256) void k_gemm2(const float* __restrict__ h,
    const ushort* __restrict__ z2, const ushort* __restrict__ wwb,
    const float* __restrict__ wb, float* __restrict__ out, int nrows)
{
    __shared__ __align__(16) ushort aL[64 * 256];
    const int tid = threadIdx.x;
    const int rb  = blockIdx.x * 64;

    {
        const int rr = tid >> 4, sl = tid & 15;
        #pragma unroll
        for (int rg = 0; rg < 4; ++rg) {
            int row = rg * 16 + rr, gr = rb + row;
            // h part: k 0..127 (slots 0..15)
            float4 v0 = make_float4(0.f,0.f,0.f,0.f), v1 = v0;
            if (gr < nrows) {
                v0 = *(const float4*)&h[(size_t)gr * 128 + sl * 8];
                v1 = *(const float4*)&h[(size_t)gr * 128 + sl * 8 + 4];
            }
            ushort t[8] = { f2bf(v0.x), f2bf(v0.y), f2bf(v0.z), f2bf(v0.w),
                            f2bf(v1.x), f2bf(v1.y), f2bf(v1.z), f2bf(v1.w) };
            int slot = sl ^ (row & 7);
            *(short8*)&aL[row * 256 + slot * 8] = *(short8*)t;
            // z2 part: k 128..255 (slots 16..31)
            short8 zv = (short8){0,0,0,0,0,0,0,0};
            if (gr < nrows) zv = *(const short8*)&z2[(size_t)gr * 128 + sl * 8];
            int slot2 = (16 + sl) ^ (row & 7);
            *(short8*)&aL[row * 256 + slot2 * 8] = zv;
        }
    }
    __syncthreads();

    const int w = tid >> 6, l = tid & 63;
    const int lr = l & 15, lk = l >> 4;

    float bs[8];
    #pragma unroll
    for (int nt = 0; nt < 8; ++nt) bs[nt] = wb[nt * 16 + lr];

    short8 a[8];
    #pragma unroll
    for (int ks = 0; ks < 8; ++ks) {
        int row  = 16 * w + lr;
        int slot = (ks * 4 + lk) ^ (row & 7);
        a[ks] = *(const short8*)&aL[row * 256 + slot * 8];
    }

    f32x4 acc[8];
    #pragma unroll
    for (int nt = 0; nt < 8; ++nt) acc[nt] = (f32x4){0.f, 0.f, 0.f, 0.f};

    #pragma unroll
    for (int nt = 0; nt < 8; ++nt)
        #pragma unroll
        for (int ks = 0; ks < 8; ++ks) {
            short8 b = *(const short8*)&wwb[(size_t)(nt * 16 + lr) * 256 + ks * 32 + lk * 8];
            acc[nt] = MFMA16(a[ks], b, acc[nt]);
        }

    // epilogue: bias + relu, rownorm over 16-lane groups, f32 store
    #pragma unroll
    for (int v = 0; v < 4; ++v) {
        float val[8], ss = 0.f;
        #pragma unroll
        for (int nt = 0; nt < 8; ++nt) {
            val[nt] = fmaxf(acc[nt][v] + bs[nt], 0.f);
            ss = fmaf(val[nt], val[nt], ss);
        }
        ss += __shfl_xor(ss, 1);
        ss += __shfl_xor(ss, 2);
        ss += __shfl_xor(ss, 4);
        ss += __shfl_xor(ss, 8);
        float nr = sqrtf(ss);
        nr = (nr == 0.f) ? 1.f : nr;
        float inv = 1.f / nr;
        int gr = rb + 16 * w + lk * 4 + v;
        if (gr < nrows) {
            #pragma unroll
            for (int nt = 0; nt < 8; ++nt)
                out[(size_t)gr * 128 + nt * 16 + lr] = val[nt] * inv;
        }
    }
}

// ---------------------------------------------------------------------------
extern "C" void kernel_launch(void* const* d_in, const int* in_sizes, int n_in,
                              void* d_out, int out_size, void* d_ws, size_t ws_size,
                              hipStream_t stream)
{
    const float* h   = (const float*)d_in[0];   // (N_SRC, 128)
    const float* wts = (const float*)d_in[1];   // (N_EDGES,)
    const int*   src = (const int*)d_in[2];
    const int*   dst = (const int*)d_in[3];
    const float* qw  = (const float*)d_in[5];   // (128,128)
    const float* qb  = (const float*)d_in[6];
    const float* www = (const float*)d_in[7];   // (128,256)
    const float* wb  = (const float*)d_in[8];
    float* out = (float*)d_out;

    const int n_src   = in_sizes[0] / 128;
    const int n_edges = in_sizes[1];
    const int n_dst   = out_size / 128;

    // workspace layout (all 16B-aligned)
    ushort* nbuf   = (ushort*)d_ws;                          // n_src*128 bf16
    ushort* z2     = nbuf + (size_t)n_src * 128;             // n_dst*128 bf16
    ushort* qwb    = z2 + (size_t)n_dst * 128;               // 16384 bf16
    ushort* wwb    = qwb + 16384;                            // 32768 bf16
    int*    eSrc   = (int*)(wwb + 32768);                    // n_edges
    float*  eW     = (float*)(eSrc + n_edges);               // n_edges
    int*    counts = (int*)(eW + n_edges);                   // n_dst
    int*    offs   = counts + n_dst;                         // n_dst + 1
    int*    cursor = offs + n_dst + 1;                       // n_dst
    int*    parts  = cursor + n_dst;                         // <= 64

    hipMemsetAsync(counts, 0, (size_t)n_dst * sizeof(int), stream);

    k_cvtW<<<48, 256, 0, stream>>>(qw, www, qwb, wwb);

    const int t1 = (n_src + 63) / 64;
    k_gemm1<<<t1, 256, 0, stream>>>(h, qwb, qb, nbuf, n_src);

    k_hist<<<1024, 256, 0, stream>>>(dst, counts, n_edges);

    const int nb = (n_dst + 1023) / 1024;
    k_scan_blk<<<nb, 1024, 0, stream>>>(counts, offs, parts, n_dst);
    k_scan_part<<<1, 64, 0, stream>>>(parts, nb);
    k_scan_add<<<nb, 1024, 0, stream>>>(offs, cursor, parts, n_dst, n_edges);

    k_scatter<<<1024, 256, 0, stream>>>(src, dst, wts, cursor, eSrc, eW, n_edges);

    const int gblocks = (n_dst + 3) / 4;
    k_gather<<<gblocks, 256, 0, stream>>>(nbuf, offs, eSrc, eW, z2, n_dst);

    const int t2 = (n_dst + 63) / 64;
    k_gemm2<<<t2, 256, 0, stream>>>(h, z2, wwb, wb, out, n_dst);
}

// Round 5
// 185.596 us; speedup vs baseline: 4.7718x; 1.2177x over previous
//
#include <hip/hip_runtime.h>
#include <math.h>

// ---------------------------------------------------------------------------
// PinSageConv, round 5: gather restructured (4 edges in flight / wave, 16B
// per-lane row slices, shfl combine), (src,w) packed int2, cvtW fused w/ hist.
//   cvt+hist: qw/ww f32->bf16  +  dst histogram            (fused kernel)
//   scan    : hierarchical 3-kernel exclusive scan
//   scatter : counting-sort edges into int2 (src,w) bins
//   gemm1   : n = relu(h @ q_w^T + q_b)      bf16 MFMA -> bf16
//   gather  : z2[d] = (sum n[src]*w)/max(sum w,1)   bf16 -> bf16
//   gemm2   : out = rownorm(relu([h_dst|z2] @ w_w^T + w_b)) -> f32
// MFMA 16x16x32_bf16 layouts (m89-verified):
//   A/B frag: lane holds [row|col = lane&15][k = (lane>>4)*8 + j], j=0..7
//   D frag  : col = lane&15, row = (lane>>4)*4 + reg
// ---------------------------------------------------------------------------

typedef __attribute__((ext_vector_type(8))) short  short8;
typedef __attribute__((ext_vector_type(8))) __bf16 bf16x8;
typedef __attribute__((ext_vector_type(4))) float  f32x4;

#define MFMA16(a, b, c) __builtin_amdgcn_mfma_f32_16x16x32_bf16( \
    __builtin_bit_cast(bf16x8, (a)), __builtin_bit_cast(bf16x8, (b)), (c), 0, 0, 0)

__device__ __forceinline__ ushort f2bf(float x) {            // RNE f32->bf16
    unsigned u = __float_as_uint(x);
    return (ushort)((u + 0x7fffu + ((u >> 16) & 1u)) >> 16);
}
__device__ __forceinline__ float bfhi(unsigned p) { return __uint_as_float(p & 0xffff0000u); }
__device__ __forceinline__ float bflo(unsigned p) { return __uint_as_float(p << 16); }

// ---------------- fused: weight cvt (blocks 0..47) + dst hist (rest) -------
__global__ __launch_bounds__(256) void k_cvt_hist(const float* __restrict__ qw,
    const float* __restrict__ ww, ushort* __restrict__ qwb, ushort* __restrict__ wwb,
    const int* __restrict__ dst, int* __restrict__ counts, int nedges)
{
    if (blockIdx.x < 48) {
        int i = (blockIdx.x * 256 + threadIdx.x) * 4;
        if (i < 16384) {
            float4 v = *(const float4*)&qw[i];
            ushort4 r; r.x = f2bf(v.x); r.y = f2bf(v.y); r.z = f2bf(v.z); r.w = f2bf(v.w);
            *(ushort4*)&qwb[i] = r;
        } else {
            int j = i - 16384;
            if (j < 32768) {
                float4 v = *(const float4*)&ww[j];
                ushort4 r; r.x = f2bf(v.x); r.y = f2bf(v.y); r.z = f2bf(v.z); r.w = f2bf(v.w);
                *(ushort4*)&wwb[j] = r;
            }
        }
    } else {
        const int stride = (gridDim.x - 48) * 256;
        for (int e = (blockIdx.x - 48) * 256 + threadIdx.x; e < nedges; e += stride)
            atomicAdd(&counts[dst[e]], 1);
    }
}

// ---------------- GEMM1: 64-row tile, 256 thr (4 waves), MFMA --------------
__global__ __launch_bounds__(256) void k_gemm1(const float* __restrict__ h,
    const ushort* __restrict__ qwb, const float* __restrict__ qb,
    ushort* __restrict__ nout, int nrows)
{
    __shared__ __align__(16) ushort aL[64 * 128];
    const int tid = threadIdx.x;
    const int rb  = blockIdx.x * 64;

    {
        const int rr = tid >> 4, sl = tid & 15;
        #pragma unroll
        for (int rg = 0; rg < 4; ++rg) {
            int row = rg * 16 + rr, gr = rb + row;
            float4 v0 = make_float4(0.f,0.f,0.f,0.f), v1 = v0;
            if (gr < nrows) {
                v0 = *(const float4*)&h[(size_t)gr * 128 + sl * 8];
                v1 = *(const float4*)&h[(size_t)gr * 128 + sl * 8 + 4];
            }
            ushort t[8] = { f2bf(v0.x), f2bf(v0.y), f2bf(v0.z), f2bf(v0.w),
                            f2bf(v1.x), f2bf(v1.y), f2bf(v1.z), f2bf(v1.w) };
            int slot = sl ^ (row & 7);
            *(short8*)&aL[row * 128 + slot * 8] = *(short8*)t;
        }
    }
    __syncthreads();

    const int w = tid >> 6, l = tid & 63;
    const int lr = l & 15, lk = l >> 4;

    float bs[8];
    #pragma unroll
    for (int nt = 0; nt < 8; ++nt) bs[nt] = qb[nt * 16 + lr];

    short8 a[4];
    #pragma unroll
    for (int ks = 0; ks < 4; ++ks) {
        int row  = 16 * w + lr;
        int slot = (ks * 4 + lk) ^ (row & 7);
        a[ks] = *(const short8*)&aL[row * 128 + slot * 8];
    }

    f32x4 acc[8];
    #pragma unroll
    for (int nt = 0; nt < 8; ++nt) acc[nt] = (f32x4){0.f, 0.f, 0.f, 0.f};

    #pragma unroll
    for (int nt = 0; nt < 8; ++nt)
        #pragma unroll
        for (int ks = 0; ks < 4; ++ks) {
            short8 b = *(const short8*)&qwb[(size_t)(nt * 16 + lr) * 128 + ks * 32 + lk * 8];
            acc[nt] = MFMA16(a[ks], b, acc[nt]);
        }

    #pragma unroll
    for (int v = 0; v < 4; ++v) {
        int gr = rb + 16 * w + lk * 4 + v;
        if (gr < nrows) {
            #pragma unroll
            for (int nt = 0; nt < 8; ++nt) {
                float x = fmaxf(acc[nt][v] + bs[nt], 0.f);
                nout[(size_t)gr * 128 + nt * 16 + lr] = f2bf(x);
            }
        }
    }
}

// ---------------- hierarchical scan ----------------------------------------
__global__ __launch_bounds__(1024) void k_scan_blk(const int* __restrict__ counts,
    int* __restrict__ offs, int* __restrict__ partials, int n)
{
    __shared__ int wtot[16];
    const int tid = threadIdx.x, lane = tid & 63, wv = tid >> 6;
    const int idx = blockIdx.x * 1024 + tid;
    int v = (idx < n) ? counts[idx] : 0;
    int x = v;
    #pragma unroll
    for (int off = 1; off < 64; off <<= 1) {
        int y = __shfl_up(x, off);
        if (lane >= off) x += y;
    }
    if (lane == 63) wtot[wv] = x;
    __syncthreads();
    if (tid == 0) {
        int r = 0;
        #pragma unroll
        for (int q = 0; q < 16; ++q) { int t = wtot[q]; wtot[q] = r; r += t; }
    }
    __syncthreads();
    if (idx < n) offs[idx] = wtot[wv] + x - v;
    if (tid == 1023) partials[blockIdx.x] = wtot[15] + x;
}

__global__ void k_scan_part(int* __restrict__ partials, int nb)
{
    const int lane = threadIdx.x;
    int v = (lane < nb) ? partials[lane] : 0;
    int x = v;
    #pragma unroll
    for (int off = 1; off < 64; off <<= 1) {
        int y = __shfl_up(x, off);
        if (lane >= off) x += y;
    }
    if (lane < nb) partials[lane] = x - v;
}

__global__ __launch_bounds__(1024) void k_scan_add(int* __restrict__ offs,
    int* __restrict__ cursor, const int* __restrict__ partials, int n, int total)
{
    const int idx = blockIdx.x * 1024 + threadIdx.x;
    if (idx < n) {
        int o = offs[idx] + partials[blockIdx.x];
        offs[idx] = o;
        cursor[idx] = o;
    }
    if (idx == 0) offs[n] = total;
}

// ---------------- scatter: pack (src, w) -> int2, 8B single store ----------
__global__ void k_scatter(const int* __restrict__ src, const int* __restrict__ dst,
    const float* __restrict__ w, int* __restrict__ cursor,
    int2* __restrict__ eSrcW, int nedges)
{
    for (int e = blockIdx.x * blockDim.x + threadIdx.x; e < nedges;
         e += gridDim.x * blockDim.x) {
        int d = dst[e];
        int pos = atomicAdd(&cursor[d], 1);
        eSrcW[pos] = make_int2(src[e], __float_as_int(w[e]));
    }
}

// ---------------- gather: wave = 1 dst row, 4 edges in flight --------------
// lane = 16*g + s : group g walks edges j0+t*4+g, lane s covers features
// s*8..s*8+7 (16B short8 load). Cross-group combine: shfl_xor 16,32.
__global__ __launch_bounds__(256) void k_gather(const ushort* __restrict__ nsrc,
    const int* __restrict__ offs, const int2* __restrict__ eSrcW,
    ushort* __restrict__ z2, int ndst)
{
    const int wave = (blockIdx.x * 256 + threadIdx.x) >> 6;
    const int lane = threadIdx.x & 63;
    const int g = lane >> 4, s = lane & 15;
    if (wave >= ndst) return;
    const int j0 = offs[wave], j1 = offs[wave + 1];

    float acc[8] = {0.f,0.f,0.f,0.f,0.f,0.f,0.f,0.f};
    float ws = 0.f;

    for (int j = j0 + g; j < j1; j += 4) {
        int2 ew = eSrcW[j];
        float we = __int_as_float(ew.y);
        short8 rv = *(const short8*)&nsrc[(size_t)ew.x * 128 + s * 8];
        uint4 p = __builtin_bit_cast(uint4, rv);
        acc[0] = fmaf(bflo(p.x), we, acc[0]);
        acc[1] = fmaf(bfhi(p.x), we, acc[1]);
        acc[2] = fmaf(bflo(p.y), we, acc[2]);
        acc[3] = fmaf(bfhi(p.y), we, acc[3]);
        acc[4] = fmaf(bflo(p.z), we, acc[4]);
        acc[5] = fmaf(bfhi(p.z), we, acc[5]);
        acc[6] = fmaf(bflo(p.w), we, acc[6]);
        acc[7] = fmaf(bfhi(p.w), we, acc[7]);
        ws += we;
    }

    #pragma unroll
    for (int i = 0; i < 8; ++i) {
        acc[i] += __shfl_xor(acc[i], 16);
        acc[i] += __shfl_xor(acc[i], 32);
    }
    ws += __shfl_xor(ws, 16);
    ws += __shfl_xor(ws, 32);

    if (g == 0) {
        float inv = 1.f / fmaxf(ws, 1.f);
        ushort t[8];
        #pragma unroll
        for (int i = 0; i < 8; ++i) t[i] = f2bf(acc[i] * inv);
        *(short8*)&z2[(size_t)wave * 128 + s * 8] = *(short8*)t;
    }
}

// ---------------- GEMM2 + row L2-norm: 64-row tile, K=256, MFMA ------------
__global__ __launch_bounds__(256) void k_gemm2(const float* __restrict__ h,
    const ushort* __restrict__ z2, const ushort* __restrict__ wwb,
    const float* __restrict__ wb, float* __restrict__ out, int nrows)
{
    __shared__ __align__(16) ushort aL[64 * 256];
    const int tid = threadIdx.x;
    const int rb  = blockIdx.x * 64;

    {
        const int rr = tid >> 4, sl = tid & 15;
        #pragma unroll
        for (int rg = 0; rg < 4; ++rg) {
            int row = rg * 16 + rr, gr = rb + row;
            float4 v0 = make_float4(0.f,0.f,0.f,0.f), v1 = v0;
            if (gr < nrows) {
                v0 = *(const float4*)&h[(size_t)gr * 128 + sl * 8];
                v1 = *(const float4*)&h[(size_t)gr * 128 + sl * 8 + 4];
            }
            ushort t[8] = { f2bf(v0.x), f2bf(v0.y), f2bf(v0.z), f2bf(v0.w),
                            f2bf(v1.x), f2bf(v1.y), f2bf(v1.z), f2bf(v1.w) };
            int slot = sl ^ (row & 7);
            *(short8*)&aL[row * 256 + slot * 8] = *(short8*)t;
            short8 zv = (short8){0,0,0,0,0,0,0,0};
            if (gr < nrows) zv = *(const short8*)&z2[(size_t)gr * 128 + sl * 8];
            int slot2 = (16 + sl) ^ (row & 7);
            *(short8*)&aL[row * 256 + slot2 * 8] = zv;
        }
    }
    __syncthreads();

    const int w = tid >> 6, l = tid & 63;
    const int lr = l & 15, lk = l >> 4;

    float bs[8];
    #pragma unroll
    for (int nt = 0; nt < 8; ++nt) bs[nt] = wb[nt * 16 + lr];

    short8 a[8];
    #pragma unroll
    for (int ks = 0; ks < 8; ++ks) {
        int row  = 16 * w + lr;
        int slot = (ks * 4 + lk) ^ (row & 7);
        a[ks] = *(const short8*)&aL[row * 256 + slot * 8];
    }

    f32x4 acc[8];
    #pragma unroll
    for (int nt = 0; nt < 8; ++nt) acc[nt] = (f32x4){0.f, 0.f, 0.f, 0.f};

    #pragma unroll
    for (int nt = 0; nt < 8; ++nt)
        #pragma unroll
        for (int ks = 0; ks < 8; ++ks) {
            short8 b = *(const short8*)&wwb[(size_t)(nt * 16 + lr) * 256 + ks * 32 + lk * 8];
            acc[nt] = MFMA16(a[ks], b, acc[nt]);
        }

    #pragma unroll
    for (int v = 0; v < 4; ++v) {
        float val[8], ss = 0.f;
        #pragma unroll
        for (int nt = 0; nt < 8; ++nt) {
            val[nt] = fmaxf(acc[nt][v] + bs[nt], 0.f);
            ss = fmaf(val[nt], val[nt], ss);
        }
        ss += __shfl_xor(ss, 1);
        ss += __shfl_xor(ss, 2);
        ss += __shfl_xor(ss, 4);
        ss += __shfl_xor(ss, 8);
        float nr = sqrtf(ss);
        nr = (nr == 0.f) ? 1.f : nr;
        float inv = 1.f / nr;
        int gr = rb + 16 * w + lk * 4 + v;
        if (gr < nrows) {
            #pragma unroll
            for (int nt = 0; nt < 8; ++nt)
                out[(size_t)gr * 128 + nt * 16 + lr] = val[nt] * inv;
        }
    }
}

// ---------------------------------------------------------------------------
extern "C" void kernel_launch(void* const* d_in, const int* in_sizes, int n_in,
                              void* d_out, int out_size, void* d_ws, size_t ws_size,
                              hipStream_t stream)
{
    const float* h   = (const float*)d_in[0];
    const float* wts = (const float*)d_in[1];
    const int*   src = (const int*)d_in[2];
    const int*   dst = (const int*)d_in[3];
    const float* qw  = (const float*)d_in[5];
    const float* qb  = (const float*)d_in[6];
    const float* www = (const float*)d_in[7];
    const float* wb  = (const float*)d_in[8];
    float* out = (float*)d_out;

    const int n_src   = in_sizes[0] / 128;
    const int n_edges = in_sizes[1];
    const int n_dst   = out_size / 128;

    // workspace layout (eSrcW offset is 8B-aligned: all prior sizes even)
    ushort* nbuf   = (ushort*)d_ws;                          // n_src*128 bf16
    ushort* z2     = nbuf + (size_t)n_src * 128;             // n_dst*128 bf16
    ushort* qwb    = z2 + (size_t)n_dst * 128;               // 16384 bf16
    ushort* wwb    = qwb + 16384;                            // 32768 bf16
    int2*   eSrcW  = (int2*)(wwb + 32768);                   // n_edges int2
    int*    counts = (int*)(eSrcW + n_edges);                // n_dst
    int*    offs   = counts + n_dst;                         // n_dst + 1
    int*    cursor = offs + n_dst + 1;                       // n_dst
    int*    parts  = cursor + n_dst;                         // <= 64

    hipMemsetAsync(counts, 0, (size_t)n_dst * sizeof(int), stream);

    k_cvt_hist<<<48 + 1024, 256, 0, stream>>>(qw, www, qwb, wwb, dst, counts, n_edges);

    const int t1 = (n_src + 63) / 64;
    k_gemm1<<<t1, 256, 0, stream>>>(h, qwb, qb, nbuf, n_src);

    const int nb = (n_dst + 1023) / 1024;
    k_scan_blk<<<nb, 1024, 0, stream>>>(counts, offs, parts, n_dst);
    k_scan_part<<<1, 64, 0, stream>>>(parts, nb);
    k_scan_add<<<nb, 1024, 0, stream>>>(offs, cursor, parts, n_dst, n_edges);

    k_scatter<<<1024, 256, 0, stream>>>(src, dst, wts, cursor, eSrcW, n_edges);

    const int gblocks = (n_dst + 3) / 4;
    k_gather<<<gblocks, 256, 0, stream>>>(nbuf, offs, eSrcW, z2, n_dst);

    const int t2 = (n_dst + 63) / 64;
    k_gemm2<<<t2, 256, 0, stream>>>(h, z2, wwb, wb, out, n_dst);
}

// Round 6
// 154.111 us; speedup vs baseline: 5.7467x; 1.2043x over previous
//
#include <hip/hip_runtime.h>
#include <math.h>

// ---------------------------------------------------------------------------
// PinSageConv, round 6: B-in-LDS GEMMs (f32->bf16 cvt fused into staging),
// swapped-operand MFMA => lane holds 4 consecutive output cols (packed
// stores, 2-shfl rownorm). 512-thr blocks, 128-row tiles, 64 KB LDS.
//   hist    : dst histogram
//   gemm1   : n = relu(h @ q_w^T + q_b)      bf16 MFMA -> bf16
//   scan    : hierarchical 3-kernel exclusive scan
//   scatter : counting-sort edges into int2 (src,w) bins
//   gather  : z2[d] = (sum n[src]*w)/max(sum w,1)   bf16 -> bf16
//   gemm2   : out = rownorm(relu([h_dst|z2] @ w_w^T + w_b)) -> f32 (2 K-phases)
// MFMA 16x16x32_bf16 (m89-verified): A/B frag lane&15 = row/col, k=(lane>>4)*8+j;
// D: col=lane&15, row=(lane>>4)*4+reg. Swapped (b,a) => lane&15 = out ROW,
// (lane>>4)*4+reg = out COL.
// ---------------------------------------------------------------------------

typedef __attribute__((ext_vector_type(8))) short  short8;
typedef __attribute__((ext_vector_type(8))) __bf16 bf16x8;
typedef __attribute__((ext_vector_type(4))) float  f32x4;

#define MFMA16(a, b, c) __builtin_amdgcn_mfma_f32_16x16x32_bf16( \
    __builtin_bit_cast(bf16x8, (a)), __builtin_bit_cast(bf16x8, (b)), (c), 0, 0, 0)

__device__ __forceinline__ ushort f2bf(float x) {            // RNE f32->bf16
    unsigned u = __float_as_uint(x);
    return (ushort)((u + 0x7fffu + ((u >> 16) & 1u)) >> 16);
}
__device__ __forceinline__ float bfhi(unsigned p) { return __uint_as_float(p & 0xffff0000u); }
__device__ __forceinline__ float bflo(unsigned p) { return __uint_as_float(p << 16); }

// cvt 8 f32 (two float4) -> short8 bf16
__device__ __forceinline__ short8 cvt8(float4 v0, float4 v1) {
    ushort t[8] = { f2bf(v0.x), f2bf(v0.y), f2bf(v0.z), f2bf(v0.w),
                    f2bf(v1.x), f2bf(v1.y), f2bf(v1.z), f2bf(v1.w) };
    return *(short8*)t;
}

// ---------------- GEMM1: 512 thr, 128-row tile, A+B in LDS -----------------
__global__ __launch_bounds__(512) void k_gemm1(const float* __restrict__ h,
    const float* __restrict__ qw, const float* __restrict__ qb,
    ushort* __restrict__ nout, int nrows)
{
    __shared__ __align__(16) ushort aL[128 * 128];   // rows x k, swizzled slots
    __shared__ __align__(16) ushort bL[128 * 128];   // cols x k, swizzled slots
    const int tid = threadIdx.x;
    const int rb  = blockIdx.x * 128;
    const int rr = tid >> 4, sl = tid & 15;

    #pragma unroll
    for (int rg = 0; rg < 4; ++rg) {
        // A rows
        int row = rg * 32 + rr, gr = rb + row;
        float4 a0 = make_float4(0.f,0.f,0.f,0.f), a1 = a0;
        if (gr < nrows) {
            a0 = *(const float4*)&h[(size_t)gr * 128 + sl * 8];
            a1 = *(const float4*)&h[(size_t)gr * 128 + sl * 8 + 4];
        }
        *(short8*)&aL[row * 128 + (sl ^ (row & 7)) * 8] = cvt8(a0, a1);
        // B cols (qw row-major [col][k])
        float4 b0 = *(const float4*)&qw[row * 128 + sl * 8];
        float4 b1 = *(const float4*)&qw[row * 128 + sl * 8 + 4];
        *(short8*)&bL[row * 128 + (sl ^ (row & 7)) * 8] = cvt8(b0, b1);
    }
    __syncthreads();

    const int w = tid >> 6, l = tid & 63;
    const int lr = l & 15, lk = l >> 4;
    const int row = w * 16 + lr;            // output row within tile

    short8 a[4];
    #pragma unroll
    for (int ks = 0; ks < 4; ++ks)
        a[ks] = *(const short8*)&aL[row * 128 + ((ks * 4 + lk) ^ (lr & 7)) * 8];

    f32x4 acc[8];
    #pragma unroll
    for (int nt = 0; nt < 8; ++nt) acc[nt] = (f32x4){0.f, 0.f, 0.f, 0.f};

    #pragma unroll
    for (int nt = 0; nt < 8; ++nt)
        #pragma unroll
        for (int ks = 0; ks < 4; ++ks) {
            short8 b = *(const short8*)&bL[(nt * 16 + lr) * 128 + ((ks * 4 + lk) ^ (lr & 7)) * 8];
            acc[nt] = MFMA16(b, a[ks], acc[nt]);   // swapped: lane&15 = row
        }

    const int gr = rb + row;
    if (gr < nrows) {
        #pragma unroll
        for (int nt = 0; nt < 8; ++nt) {
            float4 bv = *(const float4*)&qb[nt * 16 + lk * 4];
            ushort t[4];
            t[0] = f2bf(fmaxf(acc[nt][0] + bv.x, 0.f));
            t[1] = f2bf(fmaxf(acc[nt][1] + bv.y, 0.f));
            t[2] = f2bf(fmaxf(acc[nt][2] + bv.z, 0.f));
            t[3] = f2bf(fmaxf(acc[nt][3] + bv.w, 0.f));
            *(ushort4*)&nout[(size_t)gr * 128 + nt * 16 + lk * 4] = *(ushort4*)t;
        }
    }
}

// ---------------- hist ------------------------------------------------------
__global__ void k_hist(const int* __restrict__ dst, int* __restrict__ counts, int nedges)
{
    for (int e = blockIdx.x * blockDim.x + threadIdx.x; e < nedges;
         e += gridDim.x * blockDim.x)
        atomicAdd(&counts[dst[e]], 1);
}

// ---------------- hierarchical scan ----------------------------------------
__global__ __launch_bounds__(1024) void k_scan_blk(const int* __restrict__ counts,
    int* __restrict__ offs, int* __restrict__ partials, int n)
{
    __shared__ int wtot[16];
    const int tid = threadIdx.x, lane = tid & 63, wv = tid >> 6;
    const int idx = blockIdx.x * 1024 + tid;
    int v = (idx < n) ? counts[idx] : 0;
    int x = v;
    #pragma unroll
    for (int off = 1; off < 64; off <<= 1) {
        int y = __shfl_up(x, off);
        if (lane >= off) x += y;
    }
    if (lane == 63) wtot[wv] = x;
    __syncthreads();
    if (tid == 0) {
        int r = 0;
        #pragma unroll
        for (int q = 0; q < 16; ++q) { int t = wtot[q]; wtot[q] = r; r += t; }
    }
    __syncthreads();
    if (idx < n) offs[idx] = wtot[wv] + x - v;
    if (tid == 1023) partials[blockIdx.x] = wtot[15] + x;
}

__global__ void k_scan_part(int* __restrict__ partials, int nb)
{
    const int lane = threadIdx.x;
    int v = (lane < nb) ? partials[lane] : 0;
    int x = v;
    #pragma unroll
    for (int off = 1; off < 64; off <<= 1) {
        int y = __shfl_up(x, off);
        if (lane >= off) x += y;
    }
    if (lane < nb) partials[lane] = x - v;
}

__global__ __launch_bounds__(1024) void k_scan_add(int* __restrict__ offs,
    int* __restrict__ cursor, const int* __restrict__ partials, int n, int total)
{
    const int idx = blockIdx.x * 1024 + threadIdx.x;
    if (idx < n) {
        int o = offs[idx] + partials[blockIdx.x];
        offs[idx] = o;
        cursor[idx] = o;
    }
    if (idx == 0) offs[n] = total;
}

// ---------------- scatter: pack (src, w) -> int2 ---------------------------
__global__ void k_scatter(const int* __restrict__ src, const int* __restrict__ dst,
    const float* __restrict__ w, int* __restrict__ cursor,
    int2* __restrict__ eSrcW, int nedges)
{
    for (int e = blockIdx.x * blockDim.x + threadIdx.x; e < nedges;
         e += gridDim.x * blockDim.x) {
        int d = dst[e];
        int pos = atomicAdd(&cursor[d], 1);
        eSrcW[pos] = make_int2(src[e], __float_as_int(w[e]));
    }
}

// ---------------- gather: wave = 1 dst row, 4 edges in flight --------------
__global__ __launch_bounds__(256) void k_gather(const ushort* __restrict__ nsrc,
    const int* __restrict__ offs, const int2* __restrict__ eSrcW,
    ushort* __restrict__ z2, int ndst)
{
    const int wave = (blockIdx.x * 256 + threadIdx.x) >> 6;
    const int lane = threadIdx.x & 63;
    const int g = lane >> 4, s = lane & 15;
    if (wave >= ndst) return;
    const int j0 = offs[wave], j1 = offs[wave + 1];

    float acc[8] = {0.f,0.f,0.f,0.f,0.f,0.f,0.f,0.f};
    float ws = 0.f;

    for (int j = j0 + g; j < j1; j += 4) {
        int2 ew = eSrcW[j];
        float we = __int_as_float(ew.y);
        short8 rv = *(const short8*)&nsrc[(size_t)ew.x * 128 + s * 8];
        uint4 p = __builtin_bit_cast(uint4, rv);
        acc[0] = fmaf(bflo(p.x), we, acc[0]);
        acc[1] = fmaf(bfhi(p.x), we, acc[1]);
        acc[2] = fmaf(bflo(p.y), we, acc[2]);
        acc[3] = fmaf(bfhi(p.y), we, acc[3]);
        acc[4] = fmaf(bflo(p.z), we, acc[4]);
        acc[5] = fmaf(bfhi(p.z), we, acc[5]);
        acc[6] = fmaf(bflo(p.w), we, acc[6]);
        acc[7] = fmaf(bfhi(p.w), we, acc[7]);
        ws += we;
    }

    #pragma unroll
    for (int i = 0; i < 8; ++i) {
        acc[i] += __shfl_xor(acc[i], 16);
        acc[i] += __shfl_xor(acc[i], 32);
    }
    ws += __shfl_xor(ws, 16);
    ws += __shfl_xor(ws, 32);

    if (g == 0) {
        float inv = 1.f / fmaxf(ws, 1.f);
        ushort t[8];
        #pragma unroll
        for (int i = 0; i < 8; ++i) t[i] = f2bf(acc[i] * inv);
        *(short8*)&z2[(size_t)wave * 128 + s * 8] = *(short8*)t;
    }
}

// ---------------- GEMM2 + rownorm: 512 thr, 128-row tile, 2 K-phases -------
__global__ __launch_bounds__(512) void k_gemm2(const float* __restrict__ h,
    const ushort* __restrict__ z2, const float* __restrict__ ww,
    const float* __restrict__ wb, float* __restrict__ out, int nrows)
{
    __shared__ __align__(16) ushort aL[128 * 128];
    __shared__ __align__(16) ushort bL[128 * 128];
    const int tid = threadIdx.x;
    const int rb  = blockIdx.x * 128;
    const int rr = tid >> 4, sl = tid & 15;

    const int w = tid >> 6, l = tid & 63;
    const int lr = l & 15, lk = l >> 4;
    const int row = w * 16 + lr;

    f32x4 acc[8];
    #pragma unroll
    for (int nt = 0; nt < 8; ++nt) acc[nt] = (f32x4){0.f, 0.f, 0.f, 0.f};

    #pragma unroll
    for (int ph = 0; ph < 2; ++ph) {
        if (ph) __syncthreads();         // all waves done reading phase-0 LDS
        #pragma unroll
        for (int rg = 0; rg < 4; ++rg) {
            int r2 = rg * 32 + rr, gr = rb + r2;
            // A half: phase 0 from h (f32), phase 1 from z2 (bf16)
            short8 av = (short8){0,0,0,0,0,0,0,0};
            if (gr < nrows) {
                if (ph == 0) {
                    float4 a0 = *(const float4*)&h[(size_t)gr * 128 + sl * 8];
                    float4 a1 = *(const float4*)&h[(size_t)gr * 128 + sl * 8 + 4];
                    av = cvt8(a0, a1);
                } else {
                    av = *(const short8*)&z2[(size_t)gr * 128 + sl * 8];
                }
            }
            *(short8*)&aL[r2 * 128 + (sl ^ (r2 & 7)) * 8] = av;
            // B half: ww[col][ph*128 + k]
            float4 b0 = *(const float4*)&ww[r2 * 256 + ph * 128 + sl * 8];
            float4 b1 = *(const float4*)&ww[r2 * 256 + ph * 128 + sl * 8 + 4];
            *(short8*)&bL[r2 * 128 + (sl ^ (r2 & 7)) * 8] = cvt8(b0, b1);
        }
        __syncthreads();

        short8 a[4];
        #pragma unroll
        for (int ks = 0; ks < 4; ++ks)
            a[ks] = *(const short8*)&aL[row * 128 + ((ks * 4 + lk) ^ (lr & 7)) * 8];

        #pragma unroll
        for (int nt = 0; nt < 8; ++nt)
            #pragma unroll
            for (int ks = 0; ks < 4; ++ks) {
                short8 b = *(const short8*)&bL[(nt * 16 + lr) * 128 + ((ks * 4 + lk) ^ (lr & 7)) * 8];
                acc[nt] = MFMA16(b, a[ks], acc[nt]);   // swapped
            }
    }

    // bias + relu; rownorm: lane sum + shfl over lk bits (16,32)
    float val[8][4];
    float ss = 0.f;
    #pragma unroll
    for (int nt = 0; nt < 8; ++nt) {
        float4 bv = *(const float4*)&wb[nt * 16 + lk * 4];
        #pragma unroll
        for (int v = 0; v < 4; ++v) {
            float x = acc[nt][v] + ((const float*)&bv)[v];
            x = fmaxf(x, 0.f);
            val[nt][v] = x;
            ss = fmaf(x, x, ss);
        }
    }
    ss += __shfl_xor(ss, 16);
    ss += __shfl_xor(ss, 32);
    float nr = sqrtf(ss);
    nr = (nr == 0.f) ? 1.f : nr;
    float inv = 1.f / nr;

    const int gr = rb + row;
    if (gr < nrows) {
        #pragma unroll
        for (int nt = 0; nt < 8; ++nt) {
            float4 o;
            o.x = val[nt][0] * inv; o.y = val[nt][1] * inv;
            o.z = val[nt][2] * inv; o.w = val[nt][3] * inv;
            *(float4*)&out[(size_t)gr * 128 + nt * 16 + lk * 4] = o;
        }
    }
}

// ---------------------------------------------------------------------------
extern "C" void kernel_launch(void* const* d_in, const int* in_sizes, int n_in,
                              void* d_out, int out_size, void* d_ws, size_t ws_size,
                              hipStream_t stream)
{
    const float* h   = (const float*)d_in[0];
    const float* wts = (const float*)d_in[1];
    const int*   src = (const int*)d_in[2];
    const int*   dst = (const int*)d_in[3];
    const float* qw  = (const float*)d_in[5];
    const float* qb  = (const float*)d_in[6];
    const float* www = (const float*)d_in[7];
    const float* wb  = (const float*)d_in[8];
    float* out = (float*)d_out;

    const int n_src   = in_sizes[0] / 128;
    const int n_edges = in_sizes[1];
    const int n_dst   = out_size / 128;

    // workspace layout
    ushort* nbuf   = (ushort*)d_ws;                          // n_src*128 bf16
    ushort* z2     = nbuf + (size_t)n_src * 128;             // n_dst*128 bf16
    int2*   eSrcW  = (int2*)(z2 + (size_t)n_dst * 128);      // n_edges int2
    int*    counts = (int*)(eSrcW + n_edges);                // n_dst
    int*    offs   = counts + n_dst;                         // n_dst + 1
    int*    cursor = offs + n_dst + 1;                       // n_dst
    int*    parts  = cursor + n_dst;                         // <= 64

    hipMemsetAsync(counts, 0, (size_t)n_dst * sizeof(int), stream);

    k_hist<<<1024, 256, 0, stream>>>(dst, counts, n_edges);

    const int t1 = (n_src + 127) / 128;
    k_gemm1<<<t1, 512, 0, stream>>>(h, qw, qb, nbuf, n_src);

    const int nb = (n_dst + 1023) / 1024;
    k_scan_blk<<<nb, 1024, 0, stream>>>(counts, offs, parts, n_dst);
    k_scan_part<<<1, 64, 0, stream>>>(parts, nb);
    k_scan_add<<<nb, 1024, 0, stream>>>(offs, cursor, parts, n_dst, n_edges);

    k_scatter<<<1024, 256, 0, stream>>>(src, dst, wts, cursor, eSrcW, n_edges);

    const int gblocks = (n_dst + 3) / 4;
    k_gather<<<gblocks, 256, 0, stream>>>(nbuf, offs, eSrcW, z2, n_dst);

    const int t2 = (n_dst + 127) / 128;
    k_gemm2<<<t2, 512, 0, stream>>>(h, z2, www, wb, out, n_dst);
}